// Round 13
// baseline (167.256 us; speedup 1.0000x reference)
//
#include <hip/hip_runtime.h>
#include <math.h>

// Problem constants (B=4, T=2048, C=576, H=12, D=48)
#define Bn 4
#define Tn 2048
#define Cn 576
#define Hn 12
#define Dn 48
#define Mn (Bn*Tn)          // 8192 rows

// log2(e) / sqrt(48) — folded into q so attention uses exp2 directly
#define QSCALE (1.4426950408889634f * 0.14433756729740643f)

typedef short  short8  __attribute__((ext_vector_type(8)));   // 8 bf16 (4 VGPRs)
typedef short  short4x __attribute__((ext_vector_type(4)));   // 4 bf16 (8B)
typedef float  floatx4 __attribute__((ext_vector_type(4)));   // MFMA acc
typedef unsigned short ushort_t;
typedef unsigned short ushort8_t __attribute__((ext_vector_type(8))); // 16B

static __device__ __forceinline__ unsigned short f2bf(float f) {
    union { float f; unsigned int u; } v; v.f = f;
    unsigned int r = v.u + 0x7FFFu + ((v.u >> 16) & 1u);   // round-to-nearest-even
    return (unsigned short)(r >> 16);
}

// truncation-pack two fp32 -> packed bf16x2 (P >= 0, rel err <= 2^-8)
static __device__ __forceinline__ unsigned int pack_trunc(float a, float b) {
    union { float f; unsigned int u; } ua, ub; ua.f = a; ub.f = b;
    return (ua.u >> 16) | (ub.u & 0xFFFF0000u);
}

// async global->LDS, 16B per lane; lane l's data lands at lds + l*16 (lane-linear)
static __device__ __forceinline__ void gload16(void* lds, const void* g) {
    __builtin_amdgcn_global_load_lds(
        (const __attribute__((address_space(1))) void*)g,
        (__attribute__((address_space(3))) void*)lds, 16, 0, 0);
}

// counted vmcnt (T4): literal-dispatched
template<int N> static __device__ __forceinline__ void vmgate() {
    if constexpr (N == 0)      asm volatile("s_waitcnt vmcnt(0)" ::: "memory");
    else if constexpr (N == 4) asm volatile("s_waitcnt vmcnt(4)" ::: "memory");
    else if constexpr (N == 8) asm volatile("s_waitcnt vmcnt(8)" ::: "memory");
    // N == -1: no gate
}
static __device__ __forceinline__ void lgk0() {
    asm volatile("s_waitcnt lgkmcnt(0)" ::: "memory");
}
static __device__ __forceinline__ void barrier_fence() {
    asm volatile("" ::: "memory");
    __builtin_amdgcn_s_barrier();
    asm volatile("" ::: "memory");
}

// counted vm+lgk waits for the proj kernel
template<int N> static __device__ __forceinline__ void wait_vm_lg() {
    if constexpr (N == 0)
        asm volatile("s_waitcnt vmcnt(0) lgkmcnt(0)" ::: "memory");
    else if constexpr (N == 3)
        asm volatile("s_waitcnt vmcnt(3) lgkmcnt(0)" ::: "memory");
    else if constexpr (N == 6)
        asm volatile("s_waitcnt vmcnt(6) lgkmcnt(0)" ::: "memory");
    else
        static_assert(N == -12345, "unsupported waitcnt immediate");
}

// ---------------------------------------------------------------------------
// fused fp32 -> bf16 cast of all three inputs (one launch) + zb zeroing
// ---------------------------------------------------------------------------
__global__ __launch_bounds__(256)
void cast3(const float* __restrict__ a, ushort_t* __restrict__ oa, int na4,
           const float* __restrict__ b, ushort_t* __restrict__ ob, int nb4,
           const float* __restrict__ c, ushort_t* __restrict__ oc, int nc4,
           ushort_t* __restrict__ zb)
{
    int i = blockIdx.x * 256 + threadIdx.x;
    if (blockIdx.x == 0 && threadIdx.x < 16) {
        float4 z = (float4){0.f, 0.f, 0.f, 0.f};
        ((float4*)zb)[threadIdx.x] = z;          // 256 B of zeros
    }
    const float* src; ushort_t* dst; int idx;
    if (i < na4)                  { src = a; dst = oa; idx = i; }
    else if (i < na4 + nb4)       { src = b; dst = ob; idx = i - na4; }
    else if (i < na4 + nb4 + nc4) { src = c; dst = oc; idx = i - na4 - nb4; }
    else return;
    float4 v = ((const float4*)src)[idx];
    ushort4 o;
    o.x = f2bf(v.x); o.y = f2bf(v.y); o.z = f2bf(v.z); o.w = f2bf(v.w);
    ((ushort4*)dst)[idx] = o;
}

// ---------------------------------------------------------------------------
// QKV GEMM: 8-phase 256x256 schedule (proven ~49us; best of 5 structures).
// ---------------------------------------------------------------------------
__global__ __launch_bounds__(512)
void gemm_qkv(const ushort_t* __restrict__ A, const ushort_t* __restrict__ W,
              ushort_t* __restrict__ outb)
{
    __shared__ __align__(16) ushort_t Ls[8][8192];   // 8 x 16KB ring

    const int tid  = threadIdx.x;
    const int wave = tid >> 6;
    const int lane = tid & 63;
    const int m    = lane & 15;
    const int g    = lane >> 4;
    const int wr   = wave >> 2;      // m-half 0..1
    const int wn   = wave & 3;       // n-quarter 0..3

    const int bid  = blockIdx.x;
    const int xcd  = bid & 7;
    const int slot = bid >> 3;       // 0..27
    const int ng   = slot % 7;
    const int mg   = xcd + 8 * (slot / 7);
    const int m0   = mg * 256;
    const int n0g  = ng * 256;

    const int srow = lane >> 2;
    const int schk = (lane & 3) * 16;
    const char* aS0 = (const char*)A + (size_t)(m0  + (wave*2+0)*16 + srow) * (Cn*2) + schk;
    const char* aS1 = (const char*)A + (size_t)(m0  + (wave*2+1)*16 + srow) * (Cn*2) + schk;
    const char* bS0 = (const char*)W + (size_t)(n0g + (wave*2+0)*16 + srow) * (Cn*2) + schk;
    const char* bS1 = (const char*)W + (size_t)(n0g + (wave*2+1)*16 + srow) * (Cn*2) + schk;

    const int aoff = (wr * 128 + m) * 64 + g * 16;
    const int boff = (wn * 64  + m) * 64 + g * 16;

    floatx4 acc[8][4];
    #pragma unroll
    for (int i = 0; i < 8; ++i)
        #pragma unroll
        for (int j = 0; j < 4; ++j)
            acc[i][j] = (floatx4){0.f, 0.f, 0.f, 0.f};

    short8 af[8], bf01[2], bf23[2];

    auto stageA = [&](int s) {
        gload16(&Ls[s][(wave*2+0)*512], aS0); aS0 += 64;
        gload16(&Ls[s][(wave*2+1)*512], aS1); aS1 += 64;
    };
    auto stageB = [&](int s) {
        gload16(&Ls[s][(wave*2+0)*512], bS0); bS0 += 64;
        gload16(&Ls[s][(wave*2+1)*512], bS1); bS1 += 64;
    };
    auto loadA = [&](int s) {
        const char* base = (const char*)&Ls[s][0] + aoff;
        #pragma unroll
        for (int mf = 0; mf < 8; ++mf) af[mf] = *(const short8*)(base + mf * 1024);
    };
    auto loadB = [&](int s, int nf0, short8 (&bf)[2]) {
        const char* base = (const char*)&Ls[s][0] + boff;
        bf[0] = *(const short8*)(base + (nf0 + 0) * 1024);
        bf[1] = *(const short8*)(base + (nf0 + 1) * 1024);
    };
    auto mfma16 = [&](short8 (&bf)[2], int nf0) {
        __builtin_amdgcn_s_setprio(1);
        #pragma unroll
        for (int mf = 0; mf < 8; ++mf) {
            acc[mf][nf0]     = __builtin_amdgcn_mfma_f32_16x16x32_bf16(af[mf], bf[0], acc[mf][nf0],     0, 0, 0);
            acc[mf][nf0 + 1] = __builtin_amdgcn_mfma_f32_16x16x32_bf16(af[mf], bf[1], acc[mf][nf0 + 1], 0, 0, 0);
        }
        __builtin_amdgcn_s_setprio(0);
    };

    stageA(0); stageB(1); stageA(2); stageB(3); stageA(4); stageB(5);
    vmgate<8>();
    barrier_fence();

    #define QKV_TILE(s0, d0, d1, d2, d3, G1m, G3m) do {                         \
        constexpr int A0 = (s0) & 7,      B0 = ((s0)+1) & 7;                    \
        constexpr int A1 = ((s0)+2) & 7,  B1 = ((s0)+3) & 7;                    \
        constexpr int S0 = ((s0)+6) & 7,  S1 = ((s0)+7) & 7;                    \
        constexpr int S2 = ((s0)+8) & 7,  S3 = ((s0)+9) & 7;                    \
        loadA(A0); loadB(B0, 0, bf01);                                          \
        if (d0) stageA(S0);                                                     \
        barrier_fence(); lgk0();                                                \
        mfma16(bf01, 0);                                                        \
        barrier_fence();                                                        \
        loadB(B0, 2, bf23);                                                     \
        if (d1) stageB(S1);                                                     \
        barrier_fence(); lgk0();                                                \
        mfma16(bf23, 2);                                                        \
        vmgate<G1m>();                                                          \
        barrier_fence();                                                        \
        loadA(A1); loadB(B1, 0, bf01);                                          \
        if (d2) stageA(S2);                                                     \
        barrier_fence(); lgk0();                                                \
        mfma16(bf01, 0);                                                        \
        barrier_fence();                                                        \
        loadB(B1, 2, bf23);                                                     \
        if (d3) stageB(S3);                                                     \
        barrier_fence(); lgk0();                                                \
        mfma16(bf23, 2);                                                        \
        vmgate<G3m>();                                                          \
        barrier_fence();                                                        \
    } while (0)

    #pragma unroll 1
    for (int tt = 0; tt < 3; ++tt) {
        QKV_TILE(0, 1, 1, 1, 1, 8, 8);
        QKV_TILE(4, 1, 1, 1, 1, 8, 8);
    }
    QKV_TILE(0, 1, 1, 1, 1, 8, 8);   // t=6
    QKV_TILE(4, 1, 1, 0, 0, 8, 4);   // t=7
    QKV_TILE(0, 0, 0, 0, 0, 0, -1);  // t=8 (drain)
    #undef QKV_TILE

    const size_t per = (size_t)Bn * Hn * Tn * Dn;
    const int b  = m0 >> 11;
    const int t0 = m0 & 2047;
    ushort_t* Lc = (ushort_t*)&Ls[0][0];

    #pragma unroll
    for (int h2 = 0; h2 < 2; ++h2) {
        const int  nbase = n0g + h2 * 128;
        const bool vmode = (nbase >= 1152);    // 1152 = 9*128: half-uniform
        if ((wn >> 1) == h2) {
            if (!vmode) {
                #pragma unroll
                for (int mf = 0; mf < 8; ++mf)
                    #pragma unroll
                    for (int nf = 0; nf < 4; ++nf) {
                        const int  nfb = n0g + wn * 64 + nf * 16;
                        const float sc = (nfb < 576) ? QSCALE : 1.0f;
                        const int col = (wn & 1) * 64 + nf * 16 + m;
                        const int rb  = wr * 128 + mf * 16 + g * 4;
                        #pragma unroll
                        for (int r = 0; r < 4; ++r)
                            Lc[(rb + r) * 136 + col] = f2bf(acc[mf][nf][r] * sc);
                    }
            } else {
                #pragma unroll
                for (int mf = 0; mf < 8; ++mf)
                    #pragma unroll
                    for (int nf = 0; nf < 4; ++nf) {
                        const int col = (wn & 1) * 64 + nf * 16 + m;
                        const int rb  = wr * 128 + mf * 16 + g * 4;
                        ushort4 pk;
                        pk.x = f2bf(acc[mf][nf][0]); pk.y = f2bf(acc[mf][nf][1]);
                        pk.z = f2bf(acc[mf][nf][2]); pk.w = f2bf(acc[mf][nf][3]);
                        *(ushort4*)&Lc[col * 264 + rb] = pk;
                    }
            }
        }
        __syncthreads();
        if (!vmode) {
            #pragma unroll
            for (int it = 0; it < 8; ++it) {
                const int c   = tid + it * 512;
                const int row = c >> 4;
                const int c8  = (c & 15) * 8;
                const int n   = nbase + c8;
                const int which = (n >= 576);
                const int nn  = n - which * 576;
                const int h   = nn / 48, d = nn - h * 48;
                ushort_t* dst = outb + (size_t)which * per
                    + ((size_t)(b * Hn + h) * Tn + t0 + row) * Dn + d;
                *(ushort8_t*)dst = *(const ushort8_t*)&Lc[row * 136 + c8];
            }
        } else {
            #pragma unroll
            for (int it = 0; it < 8; ++it) {
                const int c   = tid + it * 512;
                const int col = c >> 5;
                const int rc  = (c & 31) * 8;
                const int n   = nbase + col;
                if (n < 1728) {
                    const int dd = n - 1152;
                    const int h  = dd / 48, d = dd - h * 48;
                    ushort_t* dst = outb + 2 * per
                        + ((size_t)(b * Hn + h) * Dn + d) * Tn + t0 + rc;
                    *(ushort8_t*)dst = *(const ushort8_t*)&Lc[col * 264 + rc];
                }
            }
        }
        __syncthreads();
    }
}

// ---------------------------------------------------------------------------
// proj GEMM: 3-buffer / 2-ahead counted-vmcnt ring (in best measured total).
// ---------------------------------------------------------------------------
template<int MTILE>
__global__ __launch_bounds__(256)
void gemm_proj(const ushort_t* __restrict__ A, const ushort_t* __restrict__ W,
               float* __restrict__ outf)
{
    constexpr int SA   = MTILE / 16;      // 8
    constexpr int NSEG = SA + 4;          // 12
    constexpr int PW   = NSEG / 4;        // 3
    constexpr int MF   = MTILE / 64;      // 2
    constexpr int NB   = 9;
    constexpr int NST  = Cn / 32;         // 18
    constexpr int AH   = 2;               // prefetch depth
    constexpr int NBUF = 3;               // AH+1 ring buffers (36KB)
    __shared__ __align__(16) ushort_t Ls[NBUF][NSEG][512];

    const int tid  = threadIdx.x;
    const int wave = tid >> 6;
    const int lane = tid & 63;
    const int m    = lane & 15;
    const int g    = lane >> 4;
    const int bid  = blockIdx.x;
    const int xcd  = bid & 7;
    const int slot = bid >> 3;
    const int n0   = (slot % NB) * 64;
    const int m0   = (xcd + 8 * (slot / NB)) * MTILE;

    floatx4 acc[MF][4];
    #pragma unroll
    for (int i = 0; i < MF; ++i)
        #pragma unroll
        for (int j = 0; j < 4; ++j)
            acc[i][j] = (floatx4){0.f, 0.f, 0.f, 0.f};

    const char* gp[PW];
    int         si[PW];
    #pragma unroll
    for (int i = 0; i < PW; ++i) {
        int s = wave + i * 4;
        si[i] = s;
        gp[i] = (s < SA)
            ? (const char*)(A + (size_t)(m0 + s * 16 + m) * Cn + g * 8)
            : (const char*)(W + (size_t)(n0 + (s - SA) * 16 + m) * Cn + g * 8);
    }

    #pragma unroll
    for (int s = 0; s < AH; ++s)
        #pragma unroll
        for (int i = 0; i < PW; ++i) { gload16(&Ls[s][si[i]][0], gp[i]); gp[i] += 64; }
    wait_vm_lg<(AH - 1) * PW>();
    __builtin_amdgcn_s_barrier();

    int buf  = 0;                          // slot holding step j
    int sbuf = AH;                         // slot for step j+AH
    for (int j = 0; j < NST; ++j) {
        if (j + AH < NST) {
            #pragma unroll
            for (int i = 0; i < PW; ++i) {
                gload16(&Ls[sbuf][si[i]][0], gp[i]);
                gp[i] += 64;
            }
        }
        short8 bf4[4];
        #pragma unroll
        for (int jj = 0; jj < 4; ++jj)
            bf4[jj] = *(const short8*)&Ls[buf][SA + jj][lane * 8];
        #pragma unroll
        for (int i = 0; i < MF; ++i) {
            short8 afr = *(const short8*)&Ls[buf][wave * MF + i][lane * 8];
            #pragma unroll
            for (int jj = 0; jj < 4; ++jj)
                acc[i][jj] = __builtin_amdgcn_mfma_f32_16x16x32_bf16(afr, bf4[jj], acc[i][jj], 0, 0, 0);
        }
        if (j < NST - AH) wait_vm_lg<(AH - 1) * PW>();
        else              wait_vm_lg<0>();
        __builtin_amdgcn_s_barrier();
        buf  = (buf  == NBUF - 1) ? 0 : buf  + 1;
        sbuf = (sbuf == NBUF - 1) ? 0 : sbuf + 1;
    }

    #pragma unroll
    for (int i = 0; i < MF; ++i) {
        #pragma unroll
        for (int r = 0; r < 4; ++r) {
            int mrow = m0 + wave * (MTILE / 4) + i * 16 + g * 4 + r;
            #pragma unroll
            for (int j = 0; j < 4; ++j)
                outf[(size_t)mrow * Cn + n0 + j * 16 + m] = acc[i][j][r];
        }
    }
}

// ---------------------------------------------------------------------------
// ROUND-20 flash attention: IN-REGISTER P^T via k-slot permutation.
// r8 model (validated by r11): LDS operand feed is the binding resource
// (~74% busy).  The P^T round-trip (4 ds_write_b64 + lgkmcnt(0) + 2
// ds_read_b128 per wave-tile) is pure transpose overhead.  MFMA sums over
// k, so the j->k-slot map is free as long as A (V^T) and B (P^T) agree.
// Choosing j(kc, g, i) = (2kc + (i>>2))*16 + g*4 + (i&3):
//  - B-operand: every value lane (q=l&15, g=l>>4) needs is ALREADY in that
//    lane: bp[kc] = {pk[2kc][0], pk[2kc][1], pk[2kc+1][0], pk[2kc+1][1]}
//    (the packed bf16 pairs computed from exp2) -- zero cross-lane traffic.
//  - A-operand: lane (d=l&15, g) reads V^T cols {kc*32+g*4+0..3} and
//    {kc*32+16+g*4+0..3} = two b64 reads in the EXISTING Vs layout at
//    base + (g>>1)*128 + m*8 + (g&1)*4 (shorts) and +256.
// LDS per wave-tile: 16xb128 + 4xb64 (~216cy) -> 8xb128 + 12xb64 (~168cy,
// 0.78x) and the per-tile lgkmcnt(0) serialization is gone.  Geometry is
// UNCHANGED (768 blocks, 8 waves x 16 q, 24 waves/CU) -- the operating
// point that r5/r6/r8/r9/r10 proved must not move.
// ---------------------------------------------------------------------------
__global__ __launch_bounds__(512, 6)
void attn_mfma(const ushort_t* __restrict__ Q, const ushort_t* __restrict__ K,
               const ushort_t* __restrict__ V, ushort_t* __restrict__ Y,
               const ushort_t* __restrict__ zb)
{
    __shared__ __align__(16) ushort_t QPs[16][512];    // Q tile (staging only now)
    __shared__ __align__(16) ushort_t Ks[2][8][512];   // [buf][(ktile t, kc)]
    __shared__ __align__(16) ushort_t Vs[2][6][512];   // [buf][(dtile t, kc)]

    const int id   = blockIdx.x;
    const int kk   = id / 48;
    const int bh   = id - kk * 48;
    const int QT   = (kk & 1) ? (kk >> 1) : (15 - (kk >> 1));   // interleave big/small
    const int tid  = threadIdx.x;
    const int wave = tid >> 6;       // 0..7
    const int lane = tid & 63;
    const int m    = lane & 15;
    const int g    = lane >> 4;
    const int q0   = QT * 128;
    const int nkt  = 2 * QT + 2;     // 64-row K tiles to process

    const ushort_t* Qp = Q + (size_t)bh * Tn * Dn;
    const ushort_t* Kp = K + (size_t)bh * Tn * Dn;
    const ushort_t* Vp = V + (size_t)bh * Dn * Tn;     // [48][T]

    {
        const char* qrp = (const char*)(Qp + (size_t)(q0 + wave * 16 + m) * Dn);
        gload16(&QPs[wave * 2 + 0][0], qrp + g * 16);
        gload16(&QPs[wave * 2 + 1][0], (g < 2) ? (qrp + 64 + g * 16) : (const char*)zb);
    }

    const bool  kpad = ((wave & 1) == 1) && (g >= 2);
    const char* kptr = kpad ? (const char*)zb
        : (const char*)(Kp + (size_t)((wave >> 1) * 16 + m) * Dn) + (wave & 1) * 64 + g * 16;
    const int   kadv = kpad ? 0 : 64 * Dn * 2;         // 64 K-rows per tile
    const char* vptr = (const char*)(Vp + (size_t)((wave >> 1) * 16 + m) * Tn)
                       + (wave & 1) * 64 + g * 16;     // valid only for wave<6
    const int   vadv = 64 * 2;                         // 64 V^T-cols per tile

    gload16(&Ks[0][wave][0], kptr); kptr += kadv;
    if (wave < 6) { gload16(&Vs[0][wave][0], vptr); vptr += vadv; }
    __syncthreads();   // drains vmcnt -> Q + tile0 ready

    short8 bq[2];
    bq[0] = *(const short8*)&QPs[wave * 2 + 0][lane * 8];
    bq[1] = *(const short8*)&QPs[wave * 2 + 1][lane * 8];

    floatx4 acc[3];
    #pragma unroll
    for (int t = 0; t < 3; ++t) acc[t] = (floatx4){0.f, 0.f, 0.f, 0.f};
    float l_tot = 0.f;
    const int qrow  = q0 + wave * 16 + m;
    const int qwmin = q0 + wave * 16;
    const int qwmax = qwmin + 15;
    const int voff  = (g >> 1) * 128 + m * 8 + (g & 1) * 4;   // V b64 base (shorts)

    for (int jt = 0; jt < nkt; ++jt) {
        const int cur = jt & 1;
        const int j0  = jt * 64;
        if (jt + 1 < nkt) {
            gload16(&Ks[cur ^ 1][wave][0], kptr); kptr += kadv;
            if (wave < 6) { gload16(&Vs[cur ^ 1][wave][0], vptr); vptr += vadv; }
        }

        if (j0 <= qwmax) {
            floatx4 s[4];
            #pragma unroll
            for (int t = 0; t < 4; ++t) {
                s[t] = (floatx4){0.f, 0.f, 0.f, 0.f};
                #pragma unroll
                for (int kc = 0; kc < 2; ++kc) {
                    short8 ak = *(const short8*)&Ks[cur][t * 2 + kc][lane * 8];
                    s[t] = __builtin_amdgcn_mfma_f32_16x16x32_bf16(ak, bq[kc], s[t], 0, 0, 0);
                }
            }

            float p[4][4];
            float lsum = 0.f;
            if (j0 + 63 > qwmin) {
                #pragma unroll
                for (int t = 0; t < 4; ++t)
                    #pragma unroll
                    for (int r = 0; r < 4; ++r) {
                        int j = j0 + t * 16 + g * 4 + r;
                        float v = (j <= qrow) ? s[t][r] : -1e30f;
                        float e = __builtin_amdgcn_exp2f(v);
                        p[t][r] = e; lsum += e;
                    }
            } else {
                #pragma unroll
                for (int t = 0; t < 4; ++t)
                    #pragma unroll
                    for (int r = 0; r < 4; ++r) {
                        float e = __builtin_amdgcn_exp2f(s[t][r]);
                        p[t][r] = e; lsum += e;
                    }
            }
            lsum += __shfl_xor(lsum, 16);
            lsum += __shfl_xor(lsum, 32);
            l_tot += lsum;

            // ---- pack P to bf16 pairs (stay in registers) ----
            unsigned int pk[4][2];
            #pragma unroll
            for (int t = 0; t < 4; ++t) {
                pk[t][0] = pack_trunc(p[t][0], p[t][1]);
                pk[t][1] = pack_trunc(p[t][2], p[t][3]);
            }

            // ---- O^T += V^T P^T, permuted k-slots (no LDS round-trip) ----
            #pragma unroll
            for (int kc = 0; kc < 2; ++kc) {
                union { unsigned int u[4]; short8 v; } bpu;
                bpu.u[0] = pk[2 * kc + 0][0];
                bpu.u[1] = pk[2 * kc + 0][1];
                bpu.u[2] = pk[2 * kc + 1][0];
                bpu.u[3] = pk[2 * kc + 1][1];
                const short8 bp = bpu.v;
                #pragma unroll
                for (int t = 0; t < 3; ++t) {
                    const ushort_t* vsb = &Vs[cur][t * 2 + kc][0];
                    short4x alo = *(const short4x*)(vsb + voff);
                    short4x ahi = *(const short4x*)(vsb + voff + 256);
                    short8 av;
                    av[0] = alo[0]; av[1] = alo[1]; av[2] = alo[2]; av[3] = alo[3];
                    av[4] = ahi[0]; av[5] = ahi[1]; av[6] = ahi[2]; av[7] = ahi[3];
                    acc[t] = __builtin_amdgcn_mfma_f32_16x16x32_bf16(av, bp, acc[t], 0, 0, 0);
                }
            }
        }

        __syncthreads();   // next tile staged (vmcnt drain) + cur-buf reads done
    }

    const float inv = 1.0f / l_tot;
    const int b = bh / Hn;
    const int h = bh - b * Hn;
    ushort_t* yp = Y + ((size_t)(b * Tn + qrow)) * Cn + h * Dn;
    #pragma unroll
    for (int t = 0; t < 3; ++t) {
        ushort4 o;
        o.x = f2bf(acc[t][0] * inv);
        o.y = f2bf(acc[t][1] * inv);
        o.z = f2bf(acc[t][2] * inv);
        o.w = f2bf(acc[t][3] * inv);
        *(ushort4*)&yp[t * 16 + g * 4] = o;
    }
}

// ---------------------------------------------------------------------------
extern "C" void kernel_launch(void* const* d_in, const int* in_sizes, int n_in,
                              void* d_out, int out_size, void* d_ws, size_t ws_size,
                              hipStream_t stream)
{
    const float* x      = (const float*)d_in[0];   // [B,T,C]
    const float* w_qkv  = (const float*)d_in[1];   // [3C,C]
    const float* w_proj = (const float*)d_in[2];   // [C,C]
    float* out = (float*)d_out;                    // [B,T,C] fp32

    const size_t per = (size_t)Bn * Hn * Tn * Dn;  // 4,718,592

    ushort_t* xb  = (ushort_t*)d_ws;               // 8192*576
    ushort_t* wqb = xb  + (size_t)Mn * Cn;         // 1728*576 (+64 pad rows read into wpb)
    ushort_t* wpb = wqb + (size_t)3 * Cn * Cn;     // 576*576
    ushort_t* qkv = wpb + (size_t)Cn * Cn;         // 3*per (q | k | v^T)
    ushort_t* yb  = qkv + 3 * per;                 // 8192*576
    ushort_t* zb  = yb  + (size_t)Mn * Cn;         // 256 B of zeros (Q/K pad source)

    // fused casts (fp32 -> bf16) + zb zeroing
    const int na4 = Mn * Cn / 4, nb4 = 3 * Cn * Cn / 4, nc4 = Cn * Cn / 4;
    cast3<<<dim3((na4 + nb4 + nc4 + 255) / 256), dim3(256), 0, stream>>>(
        x, xb, na4, w_qkv, wqb, nb4, w_proj, wpb, nc4, zb);

    // QKV GEMM (M=8192, N=1792 padded): 224 blocks, 8-phase schedule
    gemm_qkv<<<dim3(224), dim3(512), 0, stream>>>(xb, wqb, qkv);

    // causal attention (ALiBi bias is exactly zero on the unmasked region)
    attn_mfma<<<dim3((Tn / 128) * Bn * Hn), dim3(512), 0, stream>>>(
        qkv, qkv + per, qkv + 2 * per, yb, zb);

    // output projection (M=8192, N=576) -> fp32: 576 blocks, 3-buf ring
    gemm_proj<128><<<dim3((Mn / 128) * 9), dim3(256), 0, stream>>>(yb, wpb, out);
}

// Round 14
// 159.769 us; speedup vs baseline: 1.0469x; 1.0469x over previous
//
#include <hip/hip_runtime.h>
#include <math.h>

// Problem constants (B=4, T=2048, C=576, H=12, D=48)
#define Bn 4
#define Tn 2048
#define Cn 576
#define Hn 12
#define Dn 48
#define Mn (Bn*Tn)          // 8192 rows

// log2(e) / sqrt(48) — folded into q so attention uses exp2 directly
#define QSCALE (1.4426950408889634f * 0.14433756729740643f)

typedef short  short8  __attribute__((ext_vector_type(8)));   // 8 bf16 (4 VGPRs)
typedef float  floatx4 __attribute__((ext_vector_type(4)));   // MFMA acc
typedef unsigned short ushort_t;
typedef unsigned short ushort8_t __attribute__((ext_vector_type(8))); // 16B

static __device__ __forceinline__ unsigned short f2bf(float f) {
    union { float f; unsigned int u; } v; v.f = f;
    unsigned int r = v.u + 0x7FFFu + ((v.u >> 16) & 1u);   // round-to-nearest-even
    return (unsigned short)(r >> 16);
}

// truncation-pack two fp32 -> packed bf16x2 (P >= 0, rel err <= 2^-8)
static __device__ __forceinline__ unsigned int pack_trunc(float a, float b) {
    union { float f; unsigned int u; } ua, ub; ua.f = a; ub.f = b;
    return (ua.u >> 16) | (ub.u & 0xFFFF0000u);
}

// async global->LDS, 16B per lane; lane l's data lands at lds + l*16 (lane-linear)
static __device__ __forceinline__ void gload16(void* lds, const void* g) {
    __builtin_amdgcn_global_load_lds(
        (const __attribute__((address_space(1))) void*)g,
        (__attribute__((address_space(3))) void*)lds, 16, 0, 0);
}

// counted vmcnt (T4): literal-dispatched
template<int N> static __device__ __forceinline__ void vmgate() {
    if constexpr (N == 0)      asm volatile("s_waitcnt vmcnt(0)" ::: "memory");
    else if constexpr (N == 4) asm volatile("s_waitcnt vmcnt(4)" ::: "memory");
    else if constexpr (N == 8) asm volatile("s_waitcnt vmcnt(8)" ::: "memory");
    // N == -1: no gate
}
static __device__ __forceinline__ void lgk0() {
    asm volatile("s_waitcnt lgkmcnt(0)" ::: "memory");
}
static __device__ __forceinline__ void barrier_fence() {
    asm volatile("" ::: "memory");
    __builtin_amdgcn_s_barrier();
    asm volatile("" ::: "memory");
}

// counted vm+lgk waits for the proj kernel
template<int N> static __device__ __forceinline__ void wait_vm_lg() {
    if constexpr (N == 0)
        asm volatile("s_waitcnt vmcnt(0) lgkmcnt(0)" ::: "memory");
    else if constexpr (N == 3)
        asm volatile("s_waitcnt vmcnt(3) lgkmcnt(0)" ::: "memory");
    else if constexpr (N == 6)
        asm volatile("s_waitcnt vmcnt(6) lgkmcnt(0)" ::: "memory");
    else
        static_assert(N == -12345, "unsupported waitcnt immediate");
}

// ---------------------------------------------------------------------------
// fused fp32 -> bf16 cast of all three inputs (one launch) + zb zeroing
// ---------------------------------------------------------------------------
__global__ __launch_bounds__(256)
void cast3(const float* __restrict__ a, ushort_t* __restrict__ oa, int na4,
           const float* __restrict__ b, ushort_t* __restrict__ ob, int nb4,
           const float* __restrict__ c, ushort_t* __restrict__ oc, int nc4,
           ushort_t* __restrict__ zb)
{
    int i = blockIdx.x * 256 + threadIdx.x;
    if (blockIdx.x == 0 && threadIdx.x < 16) {
        float4 z = (float4){0.f, 0.f, 0.f, 0.f};
        ((float4*)zb)[threadIdx.x] = z;          // 256 B of zeros
    }
    const float* src; ushort_t* dst; int idx;
    if (i < na4)                  { src = a; dst = oa; idx = i; }
    else if (i < na4 + nb4)       { src = b; dst = ob; idx = i - na4; }
    else if (i < na4 + nb4 + nc4) { src = c; dst = oc; idx = i - na4 - nb4; }
    else return;
    float4 v = ((const float4*)src)[idx];
    ushort4 o;
    o.x = f2bf(v.x); o.y = f2bf(v.y); o.z = f2bf(v.z); o.w = f2bf(v.w);
    ((ushort4*)dst)[idx] = o;
}

// ---------------------------------------------------------------------------
// QKV GEMM: 8-phase 256x256 schedule (proven ~49us).  ROUND-21 change: the
// v-epilogue now writes the INTERLEAVED V' layout consumed by attn's
// in-register-P^T PV step.  V' per head: [32 tiles][3 t16][2 kc][64 chunks
// of 16B]; chunk (m,g) shorts i = V[time = tile*64 + kc*32 + (i>>2)*16 +
// g*4 + (i&3)][dim = t16*16 + m].  This makes attn's V staging a pure
// linear 1KB copy and its PV read a lane-unique b128 (conflict-free).
// ---------------------------------------------------------------------------
__global__ __launch_bounds__(512)
void gemm_qkv(const ushort_t* __restrict__ A, const ushort_t* __restrict__ W,
              ushort_t* __restrict__ outb)
{
    __shared__ __align__(16) ushort_t Ls[8][8192];   // 8 x 16KB ring

    const int tid  = threadIdx.x;
    const int wave = tid >> 6;
    const int lane = tid & 63;
    const int m    = lane & 15;
    const int g    = lane >> 4;
    const int wr   = wave >> 2;      // m-half 0..1
    const int wn   = wave & 3;       // n-quarter 0..3

    const int bid  = blockIdx.x;
    const int xcd  = bid & 7;
    const int slot = bid >> 3;       // 0..27
    const int ng   = slot % 7;
    const int mg   = xcd + 8 * (slot / 7);
    const int m0   = mg * 256;
    const int n0g  = ng * 256;

    const int srow = lane >> 2;
    const int schk = (lane & 3) * 16;
    const char* aS0 = (const char*)A + (size_t)(m0  + (wave*2+0)*16 + srow) * (Cn*2) + schk;
    const char* aS1 = (const char*)A + (size_t)(m0  + (wave*2+1)*16 + srow) * (Cn*2) + schk;
    const char* bS0 = (const char*)W + (size_t)(n0g + (wave*2+0)*16 + srow) * (Cn*2) + schk;
    const char* bS1 = (const char*)W + (size_t)(n0g + (wave*2+1)*16 + srow) * (Cn*2) + schk;

    const int aoff = (wr * 128 + m) * 64 + g * 16;
    const int boff = (wn * 64  + m) * 64 + g * 16;

    floatx4 acc[8][4];
    #pragma unroll
    for (int i = 0; i < 8; ++i)
        #pragma unroll
        for (int j = 0; j < 4; ++j)
            acc[i][j] = (floatx4){0.f, 0.f, 0.f, 0.f};

    short8 af[8], bf01[2], bf23[2];

    auto stageA = [&](int s) {
        gload16(&Ls[s][(wave*2+0)*512], aS0); aS0 += 64;
        gload16(&Ls[s][(wave*2+1)*512], aS1); aS1 += 64;
    };
    auto stageB = [&](int s) {
        gload16(&Ls[s][(wave*2+0)*512], bS0); bS0 += 64;
        gload16(&Ls[s][(wave*2+1)*512], bS1); bS1 += 64;
    };
    auto loadA = [&](int s) {
        const char* base = (const char*)&Ls[s][0] + aoff;
        #pragma unroll
        for (int mf = 0; mf < 8; ++mf) af[mf] = *(const short8*)(base + mf * 1024);
    };
    auto loadB = [&](int s, int nf0, short8 (&bf)[2]) {
        const char* base = (const char*)&Ls[s][0] + boff;
        bf[0] = *(const short8*)(base + (nf0 + 0) * 1024);
        bf[1] = *(const short8*)(base + (nf0 + 1) * 1024);
    };
    auto mfma16 = [&](short8 (&bf)[2], int nf0) {
        __builtin_amdgcn_s_setprio(1);
        #pragma unroll
        for (int mf = 0; mf < 8; ++mf) {
            acc[mf][nf0]     = __builtin_amdgcn_mfma_f32_16x16x32_bf16(af[mf], bf[0], acc[mf][nf0],     0, 0, 0);
            acc[mf][nf0 + 1] = __builtin_amdgcn_mfma_f32_16x16x32_bf16(af[mf], bf[1], acc[mf][nf0 + 1], 0, 0, 0);
        }
        __builtin_amdgcn_s_setprio(0);
    };

    stageA(0); stageB(1); stageA(2); stageB(3); stageA(4); stageB(5);
    vmgate<8>();
    barrier_fence();

    #define QKV_TILE(s0, d0, d1, d2, d3, G1m, G3m) do {                         \
        constexpr int A0 = (s0) & 7,      B0 = ((s0)+1) & 7;                    \
        constexpr int A1 = ((s0)+2) & 7,  B1 = ((s0)+3) & 7;                    \
        constexpr int S0 = ((s0)+6) & 7,  S1 = ((s0)+7) & 7;                    \
        constexpr int S2 = ((s0)+8) & 7,  S3 = ((s0)+9) & 7;                    \
        loadA(A0); loadB(B0, 0, bf01);                                          \
        if (d0) stageA(S0);                                                     \
        barrier_fence(); lgk0();                                                \
        mfma16(bf01, 0);                                                        \
        barrier_fence();                                                        \
        loadB(B0, 2, bf23);                                                     \
        if (d1) stageB(S1);                                                     \
        barrier_fence(); lgk0();                                                \
        mfma16(bf23, 2);                                                        \
        vmgate<G1m>();                                                          \
        barrier_fence();                                                        \
        loadA(A1); loadB(B1, 0, bf01);                                          \
        if (d2) stageA(S2);                                                     \
        barrier_fence(); lgk0();                                                \
        mfma16(bf01, 0);                                                        \
        barrier_fence();                                                        \
        loadB(B1, 2, bf23);                                                     \
        if (d3) stageB(S3);                                                     \
        barrier_fence(); lgk0();                                                \
        mfma16(bf23, 2);                                                        \
        vmgate<G3m>();                                                          \
        barrier_fence();                                                        \
    } while (0)

    #pragma unroll 1
    for (int tt = 0; tt < 3; ++tt) {
        QKV_TILE(0, 1, 1, 1, 1, 8, 8);
        QKV_TILE(4, 1, 1, 1, 1, 8, 8);
    }
    QKV_TILE(0, 1, 1, 1, 1, 8, 8);   // t=6
    QKV_TILE(4, 1, 1, 0, 0, 8, 4);   // t=7
    QKV_TILE(0, 0, 0, 0, 0, 0, -1);  // t=8 (drain)
    #undef QKV_TILE

    const size_t per = (size_t)Bn * Hn * Tn * Dn;
    const int b  = m0 >> 11;
    const int t0 = m0 & 2047;
    ushort_t* Lc = (ushort_t*)&Ls[0][0];

    #pragma unroll
    for (int h2 = 0; h2 < 2; ++h2) {
        const int  nbase = n0g + h2 * 128;
        const bool vmode = (nbase >= 1152);    // 1152 = 9*128: half-uniform
        if ((wn >> 1) == h2) {
            if (!vmode) {
                #pragma unroll
                for (int mf = 0; mf < 8; ++mf)
                    #pragma unroll
                    for (int nf = 0; nf < 4; ++nf) {
                        const int  nfb = n0g + wn * 64 + nf * 16;
                        const float sc = (nfb < 576) ? QSCALE : 1.0f;
                        const int col = (wn & 1) * 64 + nf * 16 + m;
                        const int rb  = wr * 128 + mf * 16 + g * 4;
                        #pragma unroll
                        for (int r = 0; r < 4; ++r)
                            Lc[(rb + r) * 136 + col] = f2bf(acc[mf][nf][r] * sc);
                    }
            } else {
                // transposed Lv[col(128)][264]: Lv[col][row] = V^T value
                #pragma unroll
                for (int mf = 0; mf < 8; ++mf)
                    #pragma unroll
                    for (int nf = 0; nf < 4; ++nf) {
                        const int col = (wn & 1) * 64 + nf * 16 + m;
                        const int rb  = wr * 128 + mf * 16 + g * 4;
                        ushort4 pk;
                        pk.x = f2bf(acc[mf][nf][0]); pk.y = f2bf(acc[mf][nf][1]);
                        pk.z = f2bf(acc[mf][nf][2]); pk.w = f2bf(acc[mf][nf][3]);
                        *(ushort4*)&Lc[col * 264 + rb] = pk;
                    }
            }
        }
        __syncthreads();
        if (!vmode) {
            #pragma unroll
            for (int it = 0; it < 8; ++it) {
                const int c   = tid + it * 512;
                const int row = c >> 4;
                const int c8  = (c & 15) * 8;
                const int n   = nbase + c8;
                const int which = (n >= 576);
                const int nn  = n - which * 576;
                const int h   = nn / 48, d = nn - h * 48;
                ushort_t* dst = outb + (size_t)which * per
                    + ((size_t)(b * Hn + h) * Tn + t0 + row) * Dn + d;
                *(ushort8_t*)dst = *(const ushort8_t*)&Lc[row * 136 + c8];
            }
        } else {
            // V' interleaved write: thread c -> (col, Jl, kc, gr) chunk.
            // chunk shorts: Lv[col][Jl*64+kc*32+gr*4 + 0..3] ++ [.. +16 + 0..3]
            #pragma unroll
            for (int it = 0; it < 8; ++it) {
                const int c   = tid + it * 512;
                const int col = c >> 5;
                const int rem = c & 31;
                const int Jl  = rem >> 3;
                const int kc  = (rem >> 2) & 1;
                const int gr  = rem & 3;
                const int n   = nbase + col;
                if (n < 1728) {
                    const int dd  = n - 1152;
                    const int h   = dd / 48, d = dd - h * 48;
                    const int t16 = d >> 4, mm = d & 15;
                    const int sb  = col * 264 + Jl * 64 + kc * 32 + gr * 4;
                    ushort4 lo = *(const ushort4*)&Lc[sb];
                    ushort4 hi = *(const ushort4*)&Lc[sb + 16];
                    ushort_t* dst = outb + 2 * per
                        + (size_t)(b * Hn + h) * Tn * Dn
                        + ((t0 >> 6) + Jl) * 3072 + t16 * 1024 + kc * 512
                        + (mm * 4 + gr) * 8;
                    ushort8_t v8;
                    v8[0] = lo.x; v8[1] = lo.y; v8[2] = lo.z; v8[3] = lo.w;
                    v8[4] = hi.x; v8[5] = hi.y; v8[6] = hi.z; v8[7] = hi.w;
                    *(ushort8_t*)dst = v8;
                }
            }
        }
        __syncthreads();
    }
}

// ---------------------------------------------------------------------------
// proj GEMM: 3-buffer / 2-ahead counted-vmcnt ring (in best measured total).
// ---------------------------------------------------------------------------
template<int MTILE>
__global__ __launch_bounds__(256)
void gemm_proj(const ushort_t* __restrict__ A, const ushort_t* __restrict__ W,
               float* __restrict__ outf)
{
    constexpr int SA   = MTILE / 16;      // 8
    constexpr int NSEG = SA + 4;          // 12
    constexpr int PW   = NSEG / 4;        // 3
    constexpr int MF   = MTILE / 64;      // 2
    constexpr int NB   = 9;
    constexpr int NST  = Cn / 32;         // 18
    constexpr int AH   = 2;               // prefetch depth
    constexpr int NBUF = 3;               // AH+1 ring buffers (36KB)
    __shared__ __align__(16) ushort_t Ls[NBUF][NSEG][512];

    const int tid  = threadIdx.x;
    const int wave = tid >> 6;
    const int lane = tid & 63;
    const int m    = lane & 15;
    const int g    = lane >> 4;
    const int bid  = blockIdx.x;
    const int xcd  = bid & 7;
    const int slot = bid >> 3;
    const int n0   = (slot % NB) * 64;
    const int m0   = (xcd + 8 * (slot / NB)) * MTILE;

    floatx4 acc[MF][4];
    #pragma unroll
    for (int i = 0; i < MF; ++i)
        #pragma unroll
        for (int j = 0; j < 4; ++j)
            acc[i][j] = (floatx4){0.f, 0.f, 0.f, 0.f};

    const char* gp[PW];
    int         si[PW];
    #pragma unroll
    for (int i = 0; i < PW; ++i) {
        int s = wave + i * 4;
        si[i] = s;
        gp[i] = (s < SA)
            ? (const char*)(A + (size_t)(m0 + s * 16 + m) * Cn + g * 8)
            : (const char*)(W + (size_t)(n0 + (s - SA) * 16 + m) * Cn + g * 8);
    }

    #pragma unroll
    for (int s = 0; s < AH; ++s)
        #pragma unroll
        for (int i = 0; i < PW; ++i) { gload16(&Ls[s][si[i]][0], gp[i]); gp[i] += 64; }
    wait_vm_lg<(AH - 1) * PW>();
    __builtin_amdgcn_s_barrier();

    int buf  = 0;                          // slot holding step j
    int sbuf = AH;                         // slot for step j+AH
    for (int j = 0; j < NST; ++j) {
        if (j + AH < NST) {
            #pragma unroll
            for (int i = 0; i < PW; ++i) {
                gload16(&Ls[sbuf][si[i]][0], gp[i]);
                gp[i] += 64;
            }
        }
        short8 bf4[4];
        #pragma unroll
        for (int jj = 0; jj < 4; ++jj)
            bf4[jj] = *(const short8*)&Ls[buf][SA + jj][lane * 8];
        #pragma unroll
        for (int i = 0; i < MF; ++i) {
            short8 afr = *(const short8*)&Ls[buf][wave * MF + i][lane * 8];
            #pragma unroll
            for (int jj = 0; jj < 4; ++jj)
                acc[i][jj] = __builtin_amdgcn_mfma_f32_16x16x32_bf16(afr, bf4[jj], acc[i][jj], 0, 0, 0);
        }
        if (j < NST - AH) wait_vm_lg<(AH - 1) * PW>();
        else              wait_vm_lg<0>();
        __builtin_amdgcn_s_barrier();
        buf  = (buf  == NBUF - 1) ? 0 : buf  + 1;
        sbuf = (sbuf == NBUF - 1) ? 0 : sbuf + 1;
    }

    #pragma unroll
    for (int i = 0; i < MF; ++i) {
        #pragma unroll
        for (int r = 0; r < 4; ++r) {
            int mrow = m0 + wave * (MTILE / 4) + i * 16 + g * 4 + r;
            #pragma unroll
            for (int j = 0; j < 4; ++j)
                outf[(size_t)mrow * Cn + n0 + j * 16 + m] = acc[i][j][r];
        }
    }
}

// ---------------------------------------------------------------------------
// ROUND-21 flash attention: in-register P^T (r13's verified k-slot
// permutation) + conflict-free V' b128 A-operand reads.
// r13 failed only on V-read bank conflicts (1.6M->4.9M, +4us); V' fixes the
// access pattern at the source: V staging = linear 1KB copy, PV read = one
// ds_read_b128 per (t,kc) at chunk (m*4+g)*16B (lane-unique, like ak).
// LDS per wave-tile: 16 b128 + 4 b64 + lgk-drain  ->  14 b128, no P
// round-trip, no mid-loop lgkmcnt(0).  Geometry unchanged (768 blocks,
// 8 waves x 16 q, 24 waves/CU -- the proven operating point).
// ---------------------------------------------------------------------------
__global__ __launch_bounds__(512, 6)
void attn_mfma(const ushort_t* __restrict__ Q, const ushort_t* __restrict__ K,
               const ushort_t* __restrict__ V, ushort_t* __restrict__ Y,
               const ushort_t* __restrict__ zb)
{
    __shared__ __align__(16) ushort_t QPs[16][512];    // Q tile (staging only now)
    __shared__ __align__(16) ushort_t Ks[2][8][512];   // [buf][(ktile t, kc)]
    __shared__ __align__(16) ushort_t Vs[2][6][512];   // [buf][(t16,kc) 1KB blocks]

    const int id   = blockIdx.x;
    const int kk   = id / 48;
    const int bh   = id - kk * 48;
    const int QT   = (kk & 1) ? (kk >> 1) : (15 - (kk >> 1));   // interleave big/small
    const int tid  = threadIdx.x;
    const int wave = tid >> 6;       // 0..7
    const int lane = tid & 63;
    const int m    = lane & 15;
    const int g    = lane >> 4;
    const int q0   = QT * 128;
    const int nkt  = 2 * QT + 2;     // 64-row K tiles to process

    const ushort_t* Qp = Q + (size_t)bh * Tn * Dn;
    const ushort_t* Kp = K + (size_t)bh * Tn * Dn;
    const ushort_t* Vp = V + (size_t)bh * Tn * Dn;     // V' interleaved per head

    {
        const char* qrp = (const char*)(Qp + (size_t)(q0 + wave * 16 + m) * Dn);
        gload16(&QPs[wave * 2 + 0][0], qrp + g * 16);
        gload16(&QPs[wave * 2 + 1][0], (g < 2) ? (qrp + 64 + g * 16) : (const char*)zb);
    }

    const bool  kpad = ((wave & 1) == 1) && (g >= 2);
    const char* kptr = kpad ? (const char*)zb
        : (const char*)(Kp + (size_t)((wave >> 1) * 16 + m) * Dn) + (wave & 1) * 64 + g * 16;
    const int   kadv = kpad ? 0 : 64 * Dn * 2;         // 64 K-rows per tile
    // V' staging: wave w<6 copies 1KB block w of the 6KB tile region, linear
    const char* vptr = (const char*)Vp + wave * 1024 + lane * 16;
    const int   vadv = 6144;                           // 6KB per 64-time tile

    gload16(&Ks[0][wave][0], kptr); kptr += kadv;
    if (wave < 6) { gload16(&Vs[0][wave][0], vptr); vptr += vadv; }
    __syncthreads();   // drains vmcnt -> Q + tile0 ready

    short8 bq[2];
    bq[0] = *(const short8*)&QPs[wave * 2 + 0][lane * 8];
    bq[1] = *(const short8*)&QPs[wave * 2 + 1][lane * 8];

    floatx4 acc[3];
    #pragma unroll
    for (int t = 0; t < 3; ++t) acc[t] = (floatx4){0.f, 0.f, 0.f, 0.f};
    float l_tot = 0.f;
    const int qrow  = q0 + wave * 16 + m;
    const int qwmin = q0 + wave * 16;
    const int qwmax = qwmin + 15;
    const int vchk  = (m * 4 + g) * 8;     // V' chunk short-offset (lane-unique)

    for (int jt = 0; jt < nkt; ++jt) {
        const int cur = jt & 1;
        const int j0  = jt * 64;
        if (jt + 1 < nkt) {
            gload16(&Ks[cur ^ 1][wave][0], kptr); kptr += kadv;
            if (wave < 6) { gload16(&Vs[cur ^ 1][wave][0], vptr); vptr += vadv; }
        }

        if (j0 <= qwmax) {
            floatx4 s[4];
            #pragma unroll
            for (int t = 0; t < 4; ++t) {
                s[t] = (floatx4){0.f, 0.f, 0.f, 0.f};
                #pragma unroll
                for (int kc = 0; kc < 2; ++kc) {
                    short8 ak = *(const short8*)&Ks[cur][t * 2 + kc][lane * 8];
                    s[t] = __builtin_amdgcn_mfma_f32_16x16x32_bf16(ak, bq[kc], s[t], 0, 0, 0);
                }
            }

            float p[4][4];
            float lsum = 0.f;
            if (j0 + 63 > qwmin) {
                #pragma unroll
                for (int t = 0; t < 4; ++t)
                    #pragma unroll
                    for (int r = 0; r < 4; ++r) {
                        int j = j0 + t * 16 + g * 4 + r;
                        float v = (j <= qrow) ? s[t][r] : -1e30f;
                        float e = __builtin_amdgcn_exp2f(v);
                        p[t][r] = e; lsum += e;
                    }
            } else {
                #pragma unroll
                for (int t = 0; t < 4; ++t)
                    #pragma unroll
                    for (int r = 0; r < 4; ++r) {
                        float e = __builtin_amdgcn_exp2f(s[t][r]);
                        p[t][r] = e; lsum += e;
                    }
            }
            lsum += __shfl_xor(lsum, 16);
            lsum += __shfl_xor(lsum, 32);
            l_tot += lsum;

            // ---- pack P to bf16 pairs (stay in registers) ----
            unsigned int pk[4][2];
            #pragma unroll
            for (int t = 0; t < 4; ++t) {
                pk[t][0] = pack_trunc(p[t][0], p[t][1]);
                pk[t][1] = pack_trunc(p[t][2], p[t][3]);
            }

            // ---- O^T += V^T P^T, permuted k-slots; av = lane-unique b128 ----
            #pragma unroll
            for (int kc = 0; kc < 2; ++kc) {
                union { unsigned int u[4]; short8 v; } bpu;
                bpu.u[0] = pk[2 * kc + 0][0];
                bpu.u[1] = pk[2 * kc + 0][1];
                bpu.u[2] = pk[2 * kc + 1][0];
                bpu.u[3] = pk[2 * kc + 1][1];
                const short8 bp = bpu.v;
                #pragma unroll
                for (int t = 0; t < 3; ++t) {
                    short8 av = *(const short8*)&Vs[cur][t * 2 + kc][vchk];
                    acc[t] = __builtin_amdgcn_mfma_f32_16x16x32_bf16(av, bp, acc[t], 0, 0, 0);
                }
            }
        }

        __syncthreads();   // next tile staged (vmcnt drain) + cur-buf reads done
    }

    const float inv = 1.0f / l_tot;
    const int b = bh / Hn;
    const int h = bh - b * Hn;
    ushort_t* yp = Y + ((size_t)(b * Tn + qrow)) * Cn + h * Dn;
    #pragma unroll
    for (int t = 0; t < 3; ++t) {
        ushort4 o;
        o.x = f2bf(acc[t][0] * inv);
        o.y = f2bf(acc[t][1] * inv);
        o.z = f2bf(acc[t][2] * inv);
        o.w = f2bf(acc[t][3] * inv);
        *(ushort4*)&yp[t * 16 + g * 4] = o;
    }
}

// ---------------------------------------------------------------------------
extern "C" void kernel_launch(void* const* d_in, const int* in_sizes, int n_in,
                              void* d_out, int out_size, void* d_ws, size_t ws_size,
                              hipStream_t stream)
{
    const float* x      = (const float*)d_in[0];   // [B,T,C]
    const float* w_qkv  = (const float*)d_in[1];   // [3C,C]
    const float* w_proj = (const float*)d_in[2];   // [C,C]
    float* out = (float*)d_out;                    // [B,T,C] fp32

    const size_t per = (size_t)Bn * Hn * Tn * Dn;  // 4,718,592

    ushort_t* xb  = (ushort_t*)d_ws;               // 8192*576
    ushort_t* wqb = xb  + (size_t)Mn * Cn;         // 1728*576 (+64 pad rows read into wpb)
    ushort_t* wpb = wqb + (size_t)3 * Cn * Cn;     // 576*576
    ushort_t* qkv = wpb + (size_t)Cn * Cn;         // 3*per (q | k | v' interleaved)
    ushort_t* yb  = qkv + 3 * per;                 // 8192*576
    ushort_t* zb  = yb  + (size_t)Mn * Cn;         // 256 B of zeros (Q/K pad source)

    // fused casts (fp32 -> bf16) + zb zeroing
    const int na4 = Mn * Cn / 4, nb4 = 3 * Cn * Cn / 4, nc4 = Cn * Cn / 4;
    cast3<<<dim3((na4 + nb4 + nc4 + 255) / 256), dim3(256), 0, stream>>>(
        x, xb, na4, w_qkv, wqb, nb4, w_proj, wpb, nc4, zb);

    // QKV GEMM (M=8192, N=1792 padded): 224 blocks, 8-phase schedule
    gemm_qkv<<<dim3(224), dim3(512), 0, stream>>>(xb, wqb, qkv);

    // causal attention (ALiBi bias is exactly zero on the unmasked region)
    attn_mfma<<<dim3((Tn / 128) * Bn * Hn), dim3(512), 0, stream>>>(
        qkv, qkv + per, qkv + 2 * per, yb, zb);

    // output projection (M=8192, N=576) -> fp32: 576 blocks, 3-buf ring
    gemm_proj<128><<<dim3((Mn / 128) * 9), dim3(256), 0, stream>>>(yb, wpb, out);
}